// Round 1
// baseline (8657.280 us; speedup 1.0000x reference)
//
#include <hip/hip_runtime.h>
#include <hip/hip_bf16.h>

#define H     768
#define HPAD  776     // LDS row stride (bf16 elems): +8 keeps 16B align, spreads banks
#define G3    2304
#define BATCH 16
#define TLEN  1024
#define DOUT  512
#define SLICE 32
#define WPG   24      // workgroups per group (768/32)
#define NWG   96      // 4 groups * 24
#define NTHR  384     // 6 waves
#define HSLOT 6144    // qwords per h snapshot: 16 rows * 384
#define GXSLOT 36864  // qwords per gx snapshot: 24*16*96

typedef __attribute__((ext_vector_type(8))) short short8;
typedef __attribute__((ext_vector_type(4))) float f32x4;

union U8 { short8 s; unsigned u[4]; unsigned long long q[2]; uint4 v4; };

__device__ __forceinline__ float b2f(ushort u) {
  union { unsigned int ui; float f; } v; v.ui = ((unsigned int)u) << 16; return v.f;
}
__device__ __forceinline__ ushort f2b(float f) {
  union { float f; unsigned int ui; } v; v.f = f;
  unsigned int u = v.ui;
  return (ushort)((u + 0x7fffu + ((u >> 16) & 1u)) >> 16);
}

// ---- agent-scope (cross-XCD coherent) relaxed accessors ----
__device__ __forceinline__ unsigned long long agent_ld64(const void* p) {
  return __hip_atomic_load((const unsigned long long*)p, __ATOMIC_RELAXED, __HIP_MEMORY_SCOPE_AGENT);
}
__device__ __forceinline__ unsigned agent_ld32(const void* p) {
  return __hip_atomic_load((const unsigned*)p, __ATOMIC_RELAXED, __HIP_MEMORY_SCOPE_AGENT);
}
__device__ __forceinline__ void agent_st32(void* p, unsigned v) {
  __hip_atomic_store((unsigned*)p, v, __ATOMIC_RELAXED, __HIP_MEMORY_SCOPE_AGENT);
}
__device__ __forceinline__ void agent_st64(void* p, unsigned long long v) {
  __hip_atomic_store((unsigned long long*)p, v, __ATOMIC_RELAXED, __HIP_MEMORY_SCOPE_AGENT);
}
__device__ __forceinline__ unsigned long long tagq(unsigned lo, unsigned tag) {
  return ((unsigned long long)tag << 32) | (unsigned long long)lo;
}

// 16-byte-granular load of 8 elements as bf16 fragment (plain/cached path).
__device__ __forceinline__ short8 loadA8(const void* base, bool bf, size_t eidx) {
  if (bf) return *(const short8*)((const ushort*)base + eidx);
  const uint4* f = (const uint4*)((const float*)base + eidx);
  uint4 lo = f[0];
  uint4 hi = f[1];
  U8 r;
  r.u[0] = __builtin_amdgcn_perm(lo.y, lo.x, 0x07060302);
  r.u[1] = __builtin_amdgcn_perm(lo.w, lo.z, 0x07060302);
  r.u[2] = __builtin_amdgcn_perm(hi.y, hi.x, 0x07060302);
  r.u[3] = __builtin_amdgcn_perm(hi.w, hi.z, 0x07060302);
  return r.s;
}
__device__ __forceinline__ short8 loadW8(const void* base, bool bf, size_t eidx) {
  if (bf) return *(const short8*)((const ushort*)base + eidx);
  const float* f = (const float*)base + eidx;
  short8 r;
  #pragma unroll
  for (int i = 0; i < 8; i++) r[i] = (short)f2b(f[i]);
  return r;
}
__device__ __forceinline__ float loadS(const void* p, bool bf, size_t i) {
  return bf ? b2f(((const ushort*)p)[i]) : ((const float*)p)[i];
}

__device__ __forceinline__ bool detect_bf16(const unsigned* xw, int tid, int nthr, int* sh) {
  if (tid == 0) *sh = 0;
  __syncthreads();
  int c = 0;
  for (int i = tid; i < 4096; i += nthr) {
    int e = (int)((xw[i] >> 7) & 0xFF);
    c += (e >= 110 && e <= 140) ? 1 : 0;
  }
  atomicAdd(sh, c);
  __syncthreads();
  return *sh > 2048;
}

// ---------------------------------------------------------------------------
// Persistent pipelined GRU scan — seqlock-tagged data words.
// Groups: 0=GX1 (w_ih1 @ x[t]), 1=L1 (w_hh1 @ h1 + combine),
//         2=GX2 (w_ih2 @ h1),   3=GH2 (w_hh2 @ h2 + combine, writes y2)
// Tick t computes: gx1[t], h1[t-1], gx2[t-2], h2[t-3]  (tau = t - grp).
//
// Data transport: every comm word is an aligned 8B {lo32=data, hi32=tick+1}.
// Consumers poll the words directly (tag match == data valid): flag post,
// vmcnt-drain barrier and separate data fetch collapse to ONE LLC hop.
// Buffers are 4-deep (slot = tau & 3). Overwrite anti-deps are covered by
// lagging progress flags (value = current tick, posted fire-and-forget at
// tick start; claims "my reads of tick-1 are complete"):
//   GX1 overwrites gx1[t-4]  -> needs L1-flag  >= t-2
//   L1  overwrites h1[t-5]   -> needs GX2-flag >= t-2  (peers self-implied)
//   GX2 overwrites gx2[t-6]  -> needs GH2-flag >= t-2
//   GH2 overwrites h2[t-7]   -> peers self-implied, no flag
// These are >=1-tick slack: normally satisfied on first poll. Critical cycle
// is just L1->L1 and GH2->GH2 self-chains. 2 barriers per tick.
// ---------------------------------------------------------------------------
__global__ __launch_bounds__(NTHR) void scan_kernel(
    const void* __restrict__ x,        // [16][1024][768]
    const void* __restrict__ w_ih,     // [2][2304][768]
    const void* __restrict__ w_hh,     // [2][2304][768]
    const void* __restrict__ b_ih,     // [2][2304]
    const void* __restrict__ b_hh,     // [2][2304]
    unsigned int* flags,               // [3][24][32] padded lines (zeroed)
    unsigned int* dflag,               // dtype flag out (for fc)
    unsigned long long* h1t,           // [4][16][384] tagged (zeroed)
    unsigned long long* h2t,           // [4][16][384] tagged (zeroed)
    unsigned long long* gx1t,          // [4][24][16][96] tagged (zeroed)
    unsigned long long* gx2t,          // [4][24][16][96] tagged (zeroed)
    ushort* y2)                        // [16][1024][768] bf16 (plain stores)
{
  const int wg   = blockIdx.x;
  const int grp  = wg / WPG;           // 0..3
  const int wgi  = wg % WPG;           // 0..23 -> gate columns [wgi*32, wgi*32+32)
  const int tid  = threadIdx.x;
  const int wave = tid >> 6;           // 0..5
  const int lane = tid & 63;
  const int quad = lane >> 4;          // 0..3
  const bool isL = (grp == 1 || grp == 3);

  __shared__ ushort h_lds[BATCH * HPAD];   // staged A tile (x or h), 24.8 KB
  __shared__ float ghs[96 * 17];           // MFMA C tile [gate-col][batch] (L groups)
  __shared__ float hold[BATCH * SLICE];    // persistent fp32 h slice (L groups)
  __shared__ float bih_s[96], bhh_s[96];
  __shared__ int   detsh;

  const bool isbf = detect_bf16((const unsigned*)x, tid, NTHR, &detsh);
  if (tid == 0 && wg == 0) dflag[0] = isbf ? 1u : 0u;

  for (int i = tid; i < BATCH * SLICE; i += NTHR) hold[i] = 0.0f;

  if (isL) {
    size_t boff = (grp == 3) ? (size_t)G3 : 0;
    for (int gf = tid; gf < 96; gf += NTHR) {
      size_t gidx = boff + (size_t)(gf >> 5) * H + wgi * SLICE + (gf & 31);
      bih_s[gf] = loadS(b_ih, isbf, gidx);
      bhh_s[gf] = loadS(b_hh, isbf, gidx);
    }
  }

  // ---- load this wave's B-fragments (16 gate rows x K=768) into registers --
  const void* Wmat = (grp == 0 || grp == 2) ? w_ih : w_hh;
  const size_t woff = (grp >= 2) ? (size_t)G3 * H : 0;
  const int gate   = wave >> 1;                       // 0=r,1=z,2=n
  const int gfbase = gate * SLICE + (wave & 1) * 16;  // within-wg flat gate base
  const int nrow   = gate * H + wgi * SLICE + (wave & 1) * 16 + (lane & 15);
  const size_t wbase = woff + (size_t)nrow * H + quad * 8;

  short8 bfrag[24];
  #pragma unroll
  for (int kk = 0; kk < 24; kk++)
    bfrag[kk] = loadW8(Wmat, isbf, wbase + kk * 32);

  // staging decomposition: thread -> (row b, 32-elem segment = 16 qwords)
  const int sb  = tid / 24;            // 0..15
  const int seg = tid % 24;            // 0..23

  // combine decomposition: 256 threads, pairs of columns
  const int pb = tid >> 4;             // batch
  const int pj = (tid & 15) * 2;       // column pair
  const bool pact = isL && (tid < BATCH * SLICE / 2);

  // progress flags: kind 0=L1 posts, 1=GX2 posts, 2=GH2 posts.
  // checks: GX1 reads kind0, L1 reads kind1, GX2 reads kind2.
  const int postkind = (grp == 0) ? -1 : grp - 1;
  const int chkkind  = (grp == 3) ? -1 : grp;
  const bool chklane = (chkkind >= 0) && (wave == 0) && (lane >= 32) && (lane < 32 + WPG);
  const unsigned* chkp = chklane
      ? flags + ((size_t)chkkind * WPG + (lane - 32)) * 32 : flags;

  __syncthreads();

  for (int t = 0; t < TLEN + 3; t++) {
    // fire-and-forget progress flag: "I reached tick t" == reads of t-1 done
    // (staging loads of t-1 completed before its MFMA consumed them).
    if (postkind >= 0 && tid == 0)
      agent_st32(flags + ((size_t)postkind * WPG + wgi) * 32, (unsigned)t);

    const int tau = t - grp;
    if (tau < 0 || tau >= TLEN) continue;   // uniform per WG

    // ---------------- phase 0: stage A tile + poll tagged inputs ----------
    unsigned pendS = 0, pendG = 0;
    unsigned lo[16];
    float gxv[6];
    const unsigned long long* hsrc = nullptr;
    const unsigned long long* gsrc = nullptr;
    unsigned tagS = 0, tagG = 0;

    if (grp == 0) {
      // x[t] rows, plain cached loads (handles fp32 fallback too)
      const size_t srcbase = ((size_t)sb * TLEN + tau) * H + seg * 32;
      #pragma unroll
      for (int i = 0; i < 4; i++) {
        short8 v = loadA8(x, isbf, srcbase + i * 8);
        *(short8*)&h_lds[sb * HPAD + seg * 32 + i * 8] = v;
      }
    } else {
      const int hstep = (grp == 2) ? tau : tau - 1;     // which h snapshot
      const unsigned long long* hbuf = (grp == 3) ? h2t : h1t;
      if (hstep >= 0) {
        pendS = 0xFFFFu;
        tagS  = (unsigned)(hstep + 1);
        hsrc  = hbuf + (size_t)(hstep & 3) * HSLOT + (size_t)sb * (H / 2) + seg * 16;
      }
      if (pact) {
        pendG = 0x3Fu;
        tagG  = (unsigned)(tau + 1);
        gsrc  = ((grp == 1) ? gx1t : gx2t) + (size_t)(tau & 3) * GXSLOT
              + ((size_t)wgi * BATCH + pb) * 96;
      }
    }

    bool flagok = !chklane;
    const int slkT = t - 2;
    for (;;) {
      if (pendS) {
        #pragma unroll
        for (int q = 0; q < 16; q++) if (pendS & (1u << q)) {
          unsigned long long v = agent_ld64(hsrc + q);
          if ((unsigned)(v >> 32) == tagS) { lo[q] = (unsigned)v; pendS &= ~(1u << q); }
        }
      }
      if (pendG) {
        #pragma unroll
        for (int g = 0; g < 6; g++) if (pendG & (1u << g)) {
          const int gf = (g >> 1) * 32 + pj + (g & 1);
          unsigned long long v = agent_ld64(gsrc + gf);
          if ((unsigned)(v >> 32) == tagG) {
            union { unsigned u; float f; } cv; cv.u = (unsigned)v;
            gxv[g] = cv.f; pendG &= ~(1u << g);
          }
        }
      }
      if (!flagok && (int)agent_ld32(chkp) >= slkT) flagok = true;
      if (__ballot(((pendS | pendG) != 0) || !flagok) == 0ull) break;
      __builtin_amdgcn_s_sleep(1);
    }

    if (grp != 0) {
      uint4* dst = (uint4*)&h_lds[sb * HPAD + seg * 32];
      if (tagS) {
        dst[0] = make_uint4(lo[0],  lo[1],  lo[2],  lo[3]);
        dst[1] = make_uint4(lo[4],  lo[5],  lo[6],  lo[7]);
        dst[2] = make_uint4(lo[8],  lo[9],  lo[10], lo[11]);
        dst[3] = make_uint4(lo[12], lo[13], lo[14], lo[15]);
      } else {                                   // tau==0: h = 0
        uint4 z = make_uint4(0, 0, 0, 0);
        dst[0] = z; dst[1] = z; dst[2] = z; dst[3] = z;
      }
    }
    __syncthreads();

    // ---------------- phase 1: MFMA (A from LDS, B from registers) --------
    const ushort* arow = &h_lds[(lane & 15) * HPAD + quad * 8];
    f32x4 acc0 = {0.f, 0.f, 0.f, 0.f}, acc1 = {0.f, 0.f, 0.f, 0.f};
    #pragma unroll
    for (int kk = 0; kk < 12; kk++) {
      short8 a0 = *(const short8*)(arow + kk * 32);
      short8 a1 = *(const short8*)(arow + (kk + 12) * 32);
      acc0 = __builtin_amdgcn_mfma_f32_16x16x32_bf16(a0, bfrag[kk],      acc0, 0, 0, 0);
      acc1 = __builtin_amdgcn_mfma_f32_16x16x32_bf16(a1, bfrag[kk + 12], acc1, 0, 0, 0);
    }
    f32x4 acc = acc0 + acc1;

    if (!isL) {
      // GX groups: tagged C stores straight from accumulators (no LDS tile)
      unsigned long long* outb = ((grp == 0) ? gx1t : gx2t)
          + (size_t)(tau & 3) * GXSLOT + (size_t)wgi * BATCH * 96
          + (size_t)(gfbase + (lane & 15));
      const unsigned tg = (unsigned)(tau + 1);
      #pragma unroll
      for (int i = 0; i < 4; i++) {
        union { float f; unsigned u; } cv; cv.f = acc[i];
        agent_st64(outb + (size_t)(quad * 4 + i) * 96, tagq(cv.u, tg));
      }
      __syncthreads();                 // h_lds reads done -> next tick may stage
    } else {
      // L groups: exchange C tile, then combine
      #pragma unroll
      for (int i = 0; i < 4; i++)
        ghs[(gfbase + (lane & 15)) * 17 + quad * 4 + i] = acc[i];
      __syncthreads();

      // ------------- phase 2: combine + tagged h store ---------------------
      if (pact) {
        unsigned hpack = 0;
        #pragma unroll
        for (int s = 0; s < 2; s++) {
          const int j = pj + s;
          float rpre = gxv[0 + s] + bih_s[j]      + ghs[j * 17 + pb]        + bhh_s[j];
          float zpre = gxv[2 + s] + bih_s[32 + j] + ghs[(32 + j) * 17 + pb] + bhh_s[32 + j];
          float hn   = ghs[(64 + j) * 17 + pb] + bhh_s[64 + j];
          float r = 1.0f / (1.0f + expf(-rpre));
          float z = 1.0f / (1.0f + expf(-zpre));
          float n = tanhf(gxv[4 + s] + bih_s[64 + j] + r * hn);
          float hnew = (1.0f - z) * n + z * hold[pb * SLICE + j];
          hold[pb * SLICE + j] = hnew;
          hpack |= ((unsigned)f2b(hnew)) << (16 * s);
        }
        unsigned long long* ht = (grp == 1) ? h1t : h2t;
        agent_st64(ht + (size_t)(tau & 3) * HSLOT + (size_t)pb * (H / 2)
                      + (size_t)(wgi * SLICE + pj) / 2,
                   tagq(hpack, (unsigned)(tau + 1)));
        if (grp == 3)
          *(unsigned*)&y2[((size_t)pb * TLEN + tau) * H + wgi * SLICE + pj] = hpack;
      }
      // no end barrier: h_lds already quiesced (barrier after MFMA); next
      // tick's ghs writes are fenced by the next phase-0 barrier.
    }
  }
}

// ---------------------------------------------------------------------------
// Final FC (768->512) + bias + exact GELU.  M=16384, N=512, K=768.
// ---------------------------------------------------------------------------
__global__ __launch_bounds__(256) void fc_kernel(
    const ushort* __restrict__ y2,     // [16384][768] bf16 (internal)
    const void* __restrict__ w_fc,     // [512][768]
    const void* __restrict__ b_fc,     // [512]
    const unsigned* __restrict__ dflag,
    void* __restrict__ out)            // [16384][512]
{
  const bool isbf = dflag[0] != 0u;
  const int wave = threadIdx.x >> 6;
  const int lane = threadIdx.x & 63;
  const int col  = lane & 15;
  const int quad = lane >> 4;
  const int m0 = blockIdx.x * 64 + wave * 16;
  const int n0 = blockIdx.y * 64;

  const ushort* arow = y2 + (size_t)(m0 + col) * H + quad * 8;
  const size_t bbase = (size_t)(n0 + col) * H + quad * 8;

  f32x4 acc[4];
  #pragma unroll
  for (int nt = 0; nt < 4; nt++) acc[nt] = (f32x4){0.f, 0.f, 0.f, 0.f};

  for (int kk = 0; kk < 24; kk++) {
    short8 a = *(const short8*)(arow + kk * 32);
    #pragma unroll
    for (int nt = 0; nt < 4; nt++) {
      short8 b = loadA8(w_fc, isbf, bbase + (size_t)nt * 16 * H + kk * 32);
      acc[nt] = __builtin_amdgcn_mfma_f32_16x16x32_bf16(a, b, acc[nt], 0, 0, 0);
    }
  }

  #pragma unroll
  for (int nt = 0; nt < 4; nt++) {
    #pragma unroll
    for (int i = 0; i < 4; i++) {
      int m = m0 + quad * 4 + i;
      int n = n0 + nt * 16 + col;
      float v = acc[nt][i] + loadS(b_fc, isbf, n);
      float g = 0.5f * v * (1.0f + erff(v * 0.70710678118654752f));
      if (isbf) ((ushort*)out)[(size_t)m * DOUT + n] = f2b(g);
      else      ((float*)out)[(size_t)m * DOUT + n] = g;
    }
  }
}

extern "C" void kernel_launch(void* const* d_in, const int* in_sizes, int n_in,
                              void* d_out, int out_size, void* d_ws, size_t ws_size,
                              hipStream_t stream) {
  const void* x    = d_in[0];
  const void* w_ih = d_in[1];
  const void* w_hh = d_in[2];
  const void* b_ih = d_in[3];
  const void* b_hh = d_in[4];
  const void* w_fc = d_in[5];
  const void* b_fc = d_in[6];

  char* ws = (char*)d_ws;
  // layout: [0,9216) flags[3][24][32] | [9216,9220) dflag |
  //         [9728,206336) h1t | [206336,402944) h2t |
  //         [402944,1582592) gx1t | [1582592,2762240) gx2t |
  //         [2762240,27928064) y2
  unsigned int* flags = (unsigned int*)(ws);
  unsigned int* dflag = (unsigned int*)(ws + 9216);
  unsigned long long* h1t  = (unsigned long long*)(ws + 9728);
  unsigned long long* h2t  = (unsigned long long*)(ws + 206336);
  unsigned long long* gx1t = (unsigned long long*)(ws + 402944);
  unsigned long long* gx2t = (unsigned long long*)(ws + 1582592);
  ushort* y2 = (ushort*)(ws + 2762240);

  hipMemsetAsync(ws, 0, 2762240, stream);  // flags + dflag + all tagged buffers
  scan_kernel<<<dim3(NWG), dim3(NTHR), 0, stream>>>(
      x, w_ih, w_hh, b_ih, b_hh, flags, dflag,
      h1t, h2t, gx1t, gx2t, y2);
  fc_kernel<<<dim3(16384 / 64, DOUT / 64), dim3(256), 0, stream>>>(
      y2, w_fc, b_fc, dflag, (void*)d_out);
}

// Round 2
// 4620.282 us; speedup vs baseline: 1.8738x; 1.8738x over previous
//
#include <hip/hip_runtime.h>
#include <hip/hip_bf16.h>

#define H     768
#define HPAD  776     // LDS row stride (bf16 elems): +8 keeps 16B align, spreads banks
#define G3    2304
#define BATCH 16
#define TLEN  1024
#define DOUT  512
#define SLICE 32
#define WPG   24      // workgroups per group (768/32)
#define NWG   96      // 4 groups * 24
#define NTHR  384     // 6 waves

typedef __attribute__((ext_vector_type(8))) short short8;
typedef __attribute__((ext_vector_type(4))) float f32x4;

union U8 { short8 s; unsigned u[4]; unsigned long long q[2]; uint4 v4; };

__device__ __forceinline__ float b2f(ushort u) {
  union { unsigned int ui; float f; } v; v.ui = ((unsigned int)u) << 16; return v.f;
}
__device__ __forceinline__ ushort f2b(float f) {
  union { float f; unsigned int ui; } v; v.f = f;
  unsigned int u = v.ui;
  return (ushort)((u + 0x7fffu + ((u >> 16) & 1u)) >> 16);
}

// ---- agent-scope (cross-XCD coherent) relaxed accessors ----
__device__ __forceinline__ unsigned long long agent_ld64(const void* p) {
  return __hip_atomic_load((const unsigned long long*)p, __ATOMIC_RELAXED, __HIP_MEMORY_SCOPE_AGENT);
}
__device__ __forceinline__ unsigned agent_ld32(const void* p) {
  return __hip_atomic_load((const unsigned*)p, __ATOMIC_RELAXED, __HIP_MEMORY_SCOPE_AGENT);
}
__device__ __forceinline__ void agent_st32(void* p, unsigned v) {
  __hip_atomic_store((unsigned*)p, v, __ATOMIC_RELAXED, __HIP_MEMORY_SCOPE_AGENT);
}
__device__ __forceinline__ void agent_st32f(void* p, float f) {
  union { float f; unsigned u; } cv; cv.f = f;
  __hip_atomic_store((unsigned*)p, cv.u, __ATOMIC_RELAXED, __HIP_MEMORY_SCOPE_AGENT);
}

// 16-byte-granular load of 8 elements as bf16 fragment (plain/cached path).
__device__ __forceinline__ short8 loadA8(const void* base, bool bf, size_t eidx) {
  if (bf) return *(const short8*)((const ushort*)base + eidx);
  const uint4* f = (const uint4*)((const float*)base + eidx);
  uint4 lo = f[0];
  uint4 hi = f[1];
  U8 r;
  r.u[0] = __builtin_amdgcn_perm(lo.y, lo.x, 0x07060302);
  r.u[1] = __builtin_amdgcn_perm(lo.w, lo.z, 0x07060302);
  r.u[2] = __builtin_amdgcn_perm(hi.y, hi.x, 0x07060302);
  r.u[3] = __builtin_amdgcn_perm(hi.w, hi.z, 0x07060302);
  return r.s;
}
__device__ __forceinline__ short8 loadW8(const void* base, bool bf, size_t eidx) {
  if (bf) return *(const short8*)((const ushort*)base + eidx);
  const float* f = (const float*)base + eidx;
  short8 r;
  #pragma unroll
  for (int i = 0; i < 8; i++) r[i] = (short)f2b(f[i]);
  return r;
}
__device__ __forceinline__ float loadS(const void* p, bool bf, size_t i) {
  return bf ? b2f(((const ushort*)p)[i]) : ((const float*)p)[i];
}

__device__ __forceinline__ bool detect_bf16(const unsigned* xw, int tid, int nthr, int* sh) {
  if (tid == 0) *sh = 0;
  __syncthreads();
  int c = 0;
  for (int i = tid; i < 4096; i += nthr) {
    int e = (int)((xw[i] >> 7) & 0xFF);
    c += (e >= 110 && e <= 140) ? 1 : 0;
  }
  atomicAdd(sh, c);
  __syncthreads();
  return *sh > 2048;
}

// flag line: flags[((grp*WPG + wgi)*4 + rep)*32], 128B apart
__device__ __forceinline__ unsigned* flagp(unsigned* flags, int grp, int wgi, int rep) {
  return flags + (((grp * WPG + wgi) * 4 + rep) * 32);
}

// ---------------------------------------------------------------------------
// Persistent pipelined GRU scan — flag + bulk-load transport (round-0 style),
// 4-deep buffers so all anti-dependency waits are lagging slack flags.
// Groups: 0=GX1 (w_ih1 @ x[s]), 1=L1 (w_hh1 @ h1 + combine -> h1[s]),
//         2=GX2 (w_ih2 @ h1[s]), 3=GH2 (w_hh2 @ h2 + combine -> h2[s], y2)
// Produced step: tau = t - lag, lag = {0,0,1,2}. Buffers indexed by tau&3.
// Flag value = ticks completed (posted t+1 at end of tick t).
// Wait sets (F >= t + off):
//   GX1: F_L1[wgi]  >= t-2   (gx1 slot reuse; GX1 free-runs ~2 ahead)
//   L1 : F_GX1[wgi] >= t+1 (gx1[t] ready, normally pre-satisfied)
//        F_L1 [all] >= t    (peers' h1[t-1])                 <- critical
//        F_GX2[all] >= t-2  (h1 slot reuse, slack)
//   GX2: F_L1 [all] >= t    (h1[t-1]); F_GH2[wgi] >= t-2 (gx2 slot, slack)
//   GH2: F_GX2[wgi] >= t    (gx2[tau]); F_GH2[all] >= t (peers' h2[tau-1])
// Poller count per flag replica <= 24. Data is bulk-loaded exactly once
// after the flag (never polled). L groups fast-post: per-wave vmcnt(0) +
// LDS arrival counter; last combine wave posts (no end barrier).
// ---------------------------------------------------------------------------
__global__ __launch_bounds__(NTHR) void scan_kernel(
    const void* __restrict__ x,        // [16][1024][768]
    const void* __restrict__ w_ih,     // [2][2304][768]
    const void* __restrict__ w_hh,     // [2][2304][768]
    const void* __restrict__ b_ih,     // [2][2304]
    const void* __restrict__ b_hh,     // [2][2304]
    unsigned int* flags,               // [4][24][4][32] padded flags (zeroed)
    unsigned int* dflag,               // dtype flag out (for fc)
    ushort* h1buf,                     // [4][16][768] bf16
    ushort* h2buf,                     // [4][16][768] bf16
    float*  gxbuf1,                    // [4][24][16][96] f32 (per-WG slices)
    float*  gxbuf2,                    // [4][24][16][96] f32
    ushort* y2)                        // [16][1024][768] bf16
{
  const int wg   = blockIdx.x;
  const int grp  = wg / WPG;           // 0..3
  const int wgi  = wg % WPG;           // 0..23 -> gate columns [wgi*32, wgi*32+32)
  const int tid  = threadIdx.x;
  const int wave = tid >> 6;           // 0..5
  const int lane = tid & 63;
  const int quad = lane >> 4;          // 0..3
  const bool isL = (grp == 1 || grp == 3);

  __shared__ ushort h_lds[BATCH * HPAD];   // staged A tile (x or h), 24.8 KB
  __shared__ float ghs[96 * 17];           // MFMA C tile [gate-col][batch] (L groups)
  __shared__ float hold[BATCH * SLICE];    // persistent fp32 h slice (L groups)
  __shared__ float bih_s[96], bhh_s[96];
  __shared__ unsigned donecnt[2];
  __shared__ int   detsh;

  if (tid < 2) donecnt[tid] = 0u;

  const bool isbf = detect_bf16((const unsigned*)x, tid, NTHR, &detsh);
  if (tid == 0) dflag[0] = isbf ? 1u : 0u;

  for (int i = tid; i < BATCH * SLICE; i += NTHR) hold[i] = 0.0f;

  if (isL) {
    size_t boff = (grp == 3) ? (size_t)G3 : 0;
    for (int gf = tid; gf < 96; gf += NTHR) {
      size_t gidx = boff + (size_t)(gf >> 5) * H + wgi * SLICE + (gf & 31);
      bih_s[gf] = loadS(b_ih, isbf, gidx);
      bhh_s[gf] = loadS(b_hh, isbf, gidx);
    }
  }

  // ---- per-lane poll pointer + threshold offset (wave 0 only) ----
  // replica classes: F_L1: r0=L1-all, r1=GX2-all, r2=GX1 single
  //                  F_GX1: r0=L1 single; F_GX2: r0=L1-all slack, r1=GH2 single
  //                  F_GH2: r0=GH2-all, r1=GX2 single
  const unsigned* pollp = nullptr;
  int polloff = 0;
  if (wave == 0) {
    if (grp == 0) {
      if (lane == 0) { pollp = flagp(flags, 1, wgi, 2); polloff = -2; }
    } else if (grp == 1) {
      if      (lane == 0)  { pollp = flagp(flags, 0, wgi, 0);       polloff = 1;  }
      else if (lane <= 24) { pollp = flagp(flags, 1, lane - 1, 0);  polloff = 0;  }
      else if (lane <= 48) { pollp = flagp(flags, 2, lane - 25, 0); polloff = -2; }
    } else if (grp == 2) {
      if      (lane < 24)  { pollp = flagp(flags, 1, lane, 1);      polloff = 0;  }
      else if (lane == 24) { pollp = flagp(flags, 3, wgi, 1);       polloff = -2; }
    } else {
      if      (lane == 0)  { pollp = flagp(flags, 2, wgi, 1);       polloff = 0;  }
      else if (lane <= 24) { pollp = flagp(flags, 3, lane - 1, 0);  polloff = 0;  }
    }
  }

  // ---- load this wave's B-fragments (16 gate rows x K=768) into registers --
  const void* Wmat = (grp == 0 || grp == 2) ? w_ih : w_hh;
  const size_t woff = (grp >= 2) ? (size_t)G3 * H : 0;
  const int gate   = wave >> 1;                       // 0=r,1=z,2=n
  const int gfbase = gate * SLICE + (wave & 1) * 16;  // within-wg flat gate base
  const int nrow   = gate * H + wgi * SLICE + (wave & 1) * 16 + (lane & 15);
  const size_t wbase = woff + (size_t)nrow * H + quad * 8;

  short8 bfrag[24];
  #pragma unroll
  for (int kk = 0; kk < 24; kk++)
    bfrag[kk] = loadW8(Wmat, isbf, wbase + kk * 32);

  // staging decomposition: thread -> (row b, 32-elem segment)
  const int sb  = tid / 24;            // 0..15
  const int seg = tid % 24;            // 0..23 (each 32 elems = 64B)

  // combine decomposition: 256 threads, pairs of columns
  const int pb = tid >> 4;             // batch
  const int pj = (tid & 15) * 2;       // column pair
  const bool pact = isL && (tid < BATCH * SLICE / 2);

  const int lag = (grp == 2) ? 1 : ((grp == 3) ? 2 : 0);

  __syncthreads();

  for (int t = 0; t < TLEN + 2; t++) {
    const int tau = t - lag;
    const bool active = (tau >= 0) && (tau < TLEN);

    if (!active) {
      // keep flag counters advancing; no reads this tick so no waits needed.
      __syncthreads();                 // order vs prior tick's fast-post lane
      if (tid < 4) agent_st32(flagp(flags, grp, wgi, tid), (unsigned)(t + 1));
      continue;
    }

    // ---- dependency wait ----
    if (wave == 0) {
      for (;;) {
        int v = pollp ? (int)agent_ld32(pollp) : 0x7FFFFFFF;
        if (__ballot(v < t + polloff) == 0ull) break;
        __builtin_amdgcn_s_sleep(1);
      }
    }
    __syncthreads();

    // ---- early-issue combine-phase gx loads (slack-produced earlier) ----
    unsigned long long gr01 = 0, gz01 = 0, gn01 = 0;
    if (pact) {
      const float* gxr = ((grp == 1) ? gxbuf1 : gxbuf2)
          + ((size_t)((tau & 3) * WPG + wgi) * BATCH + pb) * 96;
      gr01 = agent_ld64(gxr + pj);
      gz01 = agent_ld64(gxr + 32 + pj);
      gn01 = agent_ld64(gxr + 64 + pj);
    }

    // ---- stage A tile (16 x 768) into LDS ----
    if (grp == 0) {
      // x[tau] rows, plain cached loads (handles fp32 fallback too)
      const size_t srcbase = ((size_t)sb * TLEN + tau) * H + seg * 32;
      #pragma unroll
      for (int i = 0; i < 4; i++) {
        short8 v = loadA8(x, isbf, srcbase + i * 8);
        *(short8*)&h_lds[sb * HPAD + seg * 32 + i * 8] = v;
      }
    } else {
      const int hstep = tau - ((grp == 2) ? 0 : 1);   // h snapshot step
      ushort* dst = &h_lds[sb * HPAD + seg * 32];
      if (hstep >= 0) {
        const ushort* src = ((grp == 3) ? h2buf : h1buf)
            + (size_t)(hstep & 3) * (BATCH * H) + (size_t)sb * H + seg * 32;
        U8 a, b;
        a.q[0] = agent_ld64(src +  0); a.q[1] = agent_ld64(src +  4);
        b.q[0] = agent_ld64(src +  8); b.q[1] = agent_ld64(src + 12);
        U8 c, d;
        c.q[0] = agent_ld64(src + 16); c.q[1] = agent_ld64(src + 20);
        d.q[0] = agent_ld64(src + 24); d.q[1] = agent_ld64(src + 28);
        *(uint4*)(dst + 0)  = a.v4;
        *(uint4*)(dst + 8)  = b.v4;
        *(uint4*)(dst + 16) = c.v4;
        *(uint4*)(dst + 24) = d.v4;
      } else {
        uint4 z = make_uint4(0, 0, 0, 0);
        *(uint4*)(dst + 0)  = z; *(uint4*)(dst + 8)  = z;
        *(uint4*)(dst + 16) = z; *(uint4*)(dst + 24) = z;
      }
    }
    __syncthreads();

    // ---- MFMA: A from LDS, B from registers ----
    const ushort* arow = &h_lds[(lane & 15) * HPAD + quad * 8];
    f32x4 acc0 = {0.f, 0.f, 0.f, 0.f}, acc1 = {0.f, 0.f, 0.f, 0.f};
    #pragma unroll
    for (int kk = 0; kk < 12; kk++) {
      short8 a0 = *(const short8*)(arow + kk * 32);
      short8 a1 = *(const short8*)(arow + (kk + 12) * 32);
      acc0 = __builtin_amdgcn_mfma_f32_16x16x32_bf16(a0, bfrag[kk],      acc0, 0, 0, 0);
      acc1 = __builtin_amdgcn_mfma_f32_16x16x32_bf16(a1, bfrag[kk + 12], acc1, 0, 0, 0);
    }
    f32x4 acc = acc0 + acc1;

    if (!isL) {
      // GX groups: store C straight from accumulators (coalesced 64B runs)
      float* cbase = ((grp == 0) ? gxbuf1 : gxbuf2)
          + ((size_t)(tau & 3) * WPG + wgi) * BATCH * 96
          + (size_t)(gfbase + (lane & 15));
      #pragma unroll
      for (int i = 0; i < 4; i++)
        agent_st32f(cbase + (size_t)(quad * 4 + i) * 96, acc[i]);
      __syncthreads();                 // drains vmcnt: stores visible
      if (tid < 4) agent_st32(flagp(flags, grp, wgi, tid), (unsigned)(t + 1));
    } else {
      // L groups: exchange C tile, combine, fast-post
      #pragma unroll
      for (int i = 0; i < 4; i++)
        ghs[(gfbase + (lane & 15)) * 17 + quad * 4 + i] = acc[i];
      __syncthreads();

      if (pact) {
        union { unsigned long long q; float f[2]; } ur, uz, un;
        ur.q = gr01; uz.q = gz01; un.q = gn01;
        ushort* hout = ((grp == 1) ? h1buf : h2buf) + (size_t)(tau & 3) * (BATCH * H);
        unsigned hpack = 0;
        #pragma unroll
        for (int s = 0; s < 2; s++) {
          const int j = pj + s;
          float rpre = ur.f[s] + bih_s[j]      + ghs[j * 17 + pb]        + bhh_s[j];
          float zpre = uz.f[s] + bih_s[32 + j] + ghs[(32 + j) * 17 + pb] + bhh_s[32 + j];
          float hn   = ghs[(64 + j) * 17 + pb] + bhh_s[64 + j];
          float r = 1.0f / (1.0f + expf(-rpre));
          float z = 1.0f / (1.0f + expf(-zpre));
          float n = tanhf(un.f[s] + bih_s[64 + j] + r * hn);
          float hnew = (1.0f - z) * n + z * hold[pb * SLICE + j];
          hold[pb * SLICE + j] = hnew;
          hpack |= ((unsigned)f2b(hnew)) << (16 * s);
        }
        agent_st32(&hout[(size_t)pb * H + wgi * SLICE + pj], hpack);
        if (grp == 3)
          *(unsigned*)&y2[((size_t)pb * TLEN + tau) * H + wgi * SLICE + pj] = hpack;
      }
      // fast-post: per-wave drain + LDS arrival counter; last wave posts.
      if (tid < BATCH * SLICE / 2) {
        asm volatile("s_waitcnt vmcnt(0)" ::: "memory");
        if ((tid & 63) == 0) {
          unsigned prev = atomicAdd(&donecnt[t & 1], 1u);
          if (prev == 3u) {
            donecnt[t & 1] = 0u;
            #pragma unroll
            for (int r = 0; r < 4; r++)
              agent_st32(flagp(flags, grp, wgi, r), (unsigned)(t + 1));
          }
        }
      }
      // no end barrier: next tick's poll barrier orders LDS reuse.
    }
  }
}

// ---------------------------------------------------------------------------
// Final FC (768->512) + bias + exact GELU.  M=16384, N=512, K=768.
// ---------------------------------------------------------------------------
__global__ __launch_bounds__(256) void fc_kernel(
    const ushort* __restrict__ y2,     // [16384][768] bf16 (internal)
    const void* __restrict__ w_fc,     // [512][768]
    const void* __restrict__ b_fc,     // [512]
    const unsigned* __restrict__ dflag,
    void* __restrict__ out)            // [16384][512]
{
  const bool isbf = dflag[0] != 0u;
  const int wave = threadIdx.x >> 6;
  const int lane = threadIdx.x & 63;
  const int col  = lane & 15;
  const int quad = lane >> 4;
  const int m0 = blockIdx.x * 64 + wave * 16;
  const int n0 = blockIdx.y * 64;

  const ushort* arow = y2 + (size_t)(m0 + col) * H + quad * 8;
  const size_t bbase = (size_t)(n0 + col) * H + quad * 8;

  f32x4 acc[4];
  #pragma unroll
  for (int nt = 0; nt < 4; nt++) acc[nt] = (f32x4){0.f, 0.f, 0.f, 0.f};

  for (int kk = 0; kk < 24; kk++) {
    short8 a = *(const short8*)(arow + kk * 32);
    #pragma unroll
    for (int nt = 0; nt < 4; nt++) {
      short8 b = loadA8(w_fc, isbf, bbase + (size_t)nt * 16 * H + kk * 32);
      acc[nt] = __builtin_amdgcn_mfma_f32_16x16x32_bf16(a, b, acc[nt], 0, 0, 0);
    }
  }

  #pragma unroll
  for (int nt = 0; nt < 4; nt++) {
    #pragma unroll
    for (int i = 0; i < 4; i++) {
      int m = m0 + quad * 4 + i;
      int n = n0 + nt * 16 + col;
      float v = acc[nt][i] + loadS(b_fc, isbf, n);
      float g = 0.5f * v * (1.0f + erff(v * 0.70710678118654752f));
      if (isbf) ((ushort*)out)[(size_t)m * DOUT + n] = f2b(g);
      else      ((float*)out)[(size_t)m * DOUT + n] = g;
    }
  }
}

extern "C" void kernel_launch(void* const* d_in, const int* in_sizes, int n_in,
                              void* d_out, int out_size, void* d_ws, size_t ws_size,
                              hipStream_t stream) {
  const void* x    = d_in[0];
  const void* w_ih = d_in[1];
  const void* w_hh = d_in[2];
  const void* b_ih = d_in[3];
  const void* b_hh = d_in[4];
  const void* w_fc = d_in[5];
  const void* b_fc = d_in[6];

  char* ws = (char*)d_ws;
  // layout: [0,49152) flags[4][24][4][32] | [49152,49156) dflag |
  //         [53248,151552) h1 (4-deep) | [151552,249856) h2 (4-deep) |
  //         [249856,839680) gx1 (4-deep) | [839680,1429504) gx2 (4-deep) |
  //         [1429504,26595328) y2
  unsigned int* flags = (unsigned int*)(ws);
  unsigned int* dflag = (unsigned int*)(ws + 49152);
  ushort* h1buf  = (ushort*)(ws + 53248);
  ushort* h2buf  = (ushort*)(ws + 151552);
  float*  gxbuf1 = (float*)(ws + 249856);
  float*  gxbuf2 = (float*)(ws + 839680);
  ushort* y2     = (ushort*)(ws + 1429504);

  hipMemsetAsync(ws, 0, 49156, stream);  // flags + dflag only (data is flag-gated)
  scan_kernel<<<dim3(NWG), dim3(NTHR), 0, stream>>>(
      x, w_ih, w_hh, b_ih, b_hh, flags, dflag,
      h1buf, h2buf, gxbuf1, gxbuf2, y2);
  fc_kernel<<<dim3(16384 / 64, DOUT / 64), dim3(256), 0, stream>>>(
      y2, w_fc, b_fc, dflag, (void*)d_out);
}

// Round 4
// 3675.834 us; speedup vs baseline: 2.3552x; 1.2569x over previous
//
#include <hip/hip_runtime.h>
#include <hip/hip_bf16.h>

#define H     768
#define G3    2304
#define BATCH 16
#define TLEN  1024
#define DOUT  512
#define SLICE 32
#define WPG   24      // workgroups per group (768/32)
#define NWG   96      // 4 groups * 24
#define NTHR  384     // 6 waves

typedef __attribute__((ext_vector_type(8))) short short8;
typedef __attribute__((ext_vector_type(4))) float f32x4;
typedef __attribute__((ext_vector_type(4))) unsigned int u32x4;

union U8 { short8 s; unsigned u[4]; unsigned long long q[2]; };

__device__ __forceinline__ float b2f(ushort u) {
  union { unsigned int ui; float f; } v; v.ui = ((unsigned int)u) << 16; return v.f;
}
__device__ __forceinline__ ushort f2b(float f) {
  union { float f; unsigned int ui; } v; v.f = f;
  unsigned int u = v.ui;
  return (ushort)((u + 0x7fffu + ((u >> 16) & 1u)) >> 16);
}

// ---- agent-scope (cross-XCD coherent) relaxed accessors ----
__device__ __forceinline__ unsigned long long agent_ld64(const void* p) {
  return __hip_atomic_load((const unsigned long long*)p, __ATOMIC_RELAXED, __HIP_MEMORY_SCOPE_AGENT);
}
__device__ __forceinline__ unsigned agent_ld32(const void* p) {
  return __hip_atomic_load((const unsigned*)p, __ATOMIC_RELAXED, __HIP_MEMORY_SCOPE_AGENT);
}
__device__ __forceinline__ void agent_st32(void* p, unsigned v) {
  __hip_atomic_store((unsigned*)p, v, __ATOMIC_RELAXED, __HIP_MEMORY_SCOPE_AGENT);
}
__device__ __forceinline__ void agent_st64(void* p, unsigned long long v) {
  __hip_atomic_store((unsigned long long*)p, v, __ATOMIC_RELAXED, __HIP_MEMORY_SCOPE_AGENT);
}

// 64B coherent (agent-scope, L1-bypassing) load: 4 x dwordx4 with sc0 sc1.
__device__ __forceinline__ void ld64B_agent(const void* p, u32x4* r) {
  asm volatile(
    "global_load_dwordx4 %0, %4, off sc0 sc1\n\t"
    "global_load_dwordx4 %1, %4, off offset:16 sc0 sc1\n\t"
    "global_load_dwordx4 %2, %4, off offset:32 sc0 sc1\n\t"
    "global_load_dwordx4 %3, %4, off offset:48 sc0 sc1\n\t"
    "s_waitcnt vmcnt(0)"
    : "=&v"(r[0]), "=&v"(r[1]), "=&v"(r[2]), "=&v"(r[3])
    : "v"(p) : "memory");
}

// 16-byte-granular load of 8 elements as bf16 fragment (plain/cached path).
__device__ __forceinline__ short8 loadA8(const void* base, bool bf, size_t eidx) {
  if (bf) return *(const short8*)((const ushort*)base + eidx);
  const uint4* f = (const uint4*)((const float*)base + eidx);
  uint4 lo = f[0];
  uint4 hi = f[1];
  U8 r;
  r.u[0] = __builtin_amdgcn_perm(lo.y, lo.x, 0x07060302);
  r.u[1] = __builtin_amdgcn_perm(lo.w, lo.z, 0x07060302);
  r.u[2] = __builtin_amdgcn_perm(hi.y, hi.x, 0x07060302);
  r.u[3] = __builtin_amdgcn_perm(hi.w, hi.z, 0x07060302);
  return r.s;
}
__device__ __forceinline__ short8 loadW8(const void* base, bool bf, size_t eidx) {
  if (bf) return *(const short8*)((const ushort*)base + eidx);
  const float* f = (const float*)base + eidx;
  short8 r;
  #pragma unroll
  for (int i = 0; i < 8; i++) r[i] = (short)f2b(f[i]);
  return r;
}
__device__ __forceinline__ float loadS(const void* p, bool bf, size_t i) {
  return bf ? b2f(((const ushort*)p)[i]) : ((const float*)p)[i];
}

__device__ __forceinline__ bool detect_bf16(const unsigned* xw, int tid, int nthr, int* sh) {
  if (tid == 0) *sh = 0;
  __syncthreads();
  int c = 0;
  for (int i = tid; i < 4096; i += nthr) {
    int e = (int)((xw[i] >> 7) & 0xFF);
    c += (e >= 110 && e <= 140) ? 1 : 0;
  }
  atomicAdd(sh, c);
  __syncthreads();
  return *sh > 2048;
}

// flag line: flags[((grp*WPG + wgi)*4 + rep)*32], 128B apart
__device__ __forceinline__ unsigned* flagp(unsigned* flags, int grp, int wgi, int rep) {
  return flags + (((grp * WPG + wgi) * 4 + rep) * 32);
}

// ---------------------------------------------------------------------------
// Persistent pipelined GRU scan (round-0 transport + slack + LDS swizzle).
// Groups: 0=GX1 (w_ih1 @ x[s]),  1=L1 (w_hh1 @ h1 + combine -> h1[s]),
//         2=GX2 (w_ih2 @ h1[s]), 3=GH2 (w_hh2 @ h2 + combine -> y2[s]=h2[s])
// lag = {0,1,2,4}; tau = t - lag. Buffers gx1/gx2/h1 4-deep (slot = step&3);
// y2 holds the full h2 history (no separate h2 buffer).
// Flag value = ticks completed (posted t+1 after end-of-tick barrier).
// Waits (flag >= t + off):
//   GX1: F_L1 r2[wgi]  off -2   (gx1 slot reuse; GX1 free-runs ~2-3 ahead)
//   L1 : F_GX1 r0[wgi] off  0   (gx1[t-1] ready; pre-satisfied in steady state)
//        F_L1  r0[all] off  0   (peers' h1[t-2])               <- critical
//        F_GX2 r0[all] off -2   (h1 slot reuse, 2 ticks slack)
//   GX2: F_L1  r1[all] off  0   (h1[t-2] ready; true dependency)
//        F_GH2 r1[wgi] off -1   (gx2 slot reuse, 1 tick slack)
//   GH2: F_GX2 r1[wgi] off -1   (gx2[t-4] ready, 1 tick slack)
//        F_GH2 r0[all] off  0   (peers' h2[t-5] in y2)         <- critical
// Poller count per flag line <= 24; data is bulk-loaded once, never polled.
// LDS tile swizzle: 16B unit u of row r lives at r*768 + (u^(r&7))*8 elems
// (G4 XOR fix; row stride 1536B). Applied on both write and read sides.
// ---------------------------------------------------------------------------
__global__ __launch_bounds__(NTHR) void scan_kernel(
    const void* __restrict__ x,        // [16][1024][768]
    const void* __restrict__ w_ih,     // [2][2304][768]
    const void* __restrict__ w_hh,     // [2][2304][768]
    const void* __restrict__ b_ih,     // [2][2304]
    const void* __restrict__ b_hh,     // [2][2304]
    unsigned int* flags,               // [4][24][4][32] padded flags (zeroed)
    unsigned int* dflag,               // dtype flag out (for fc)
    ushort* h1buf,                     // [4][16][768] bf16
    float*  gxbuf1,                    // [4][24][16][96] f32 (per-WG slices)
    float*  gxbuf2,                    // [4][24][16][96] f32
    ushort* y2)                        // [16][1024][768] bf16 (= h2 history)
{
  const int wg   = blockIdx.x;
  const int grp  = wg / WPG;           // 0..3
  const int wgi  = wg % WPG;           // 0..23 -> gate columns [wgi*32, wgi*32+32)
  const int tid  = threadIdx.x;
  const int wave = tid >> 6;           // 0..5
  const int lane = tid & 63;
  const int quad = lane >> 4;          // 0..3
  const bool isL = (grp == 1 || grp == 3);

  __shared__ ushort h_lds[BATCH * H];      // staged A tile (swizzled), 24 KB
  __shared__ float ghs[96 * 17];           // MFMA C tile [gate-col][batch]
  __shared__ float hold[BATCH * SLICE];    // persistent fp32 h slice
  __shared__ float bih_s[96], bhh_s[96];
  __shared__ int   detsh;

  const bool isbf = detect_bf16((const unsigned*)x, tid, NTHR, &detsh);
  if (tid == 0) dflag[0] = isbf ? 1u : 0u;

  for (int i = tid; i < BATCH * SLICE; i += NTHR) hold[i] = 0.0f;

  if (isL) {
    size_t boff = (grp == 3) ? (size_t)G3 : 0;
    for (int gf = tid; gf < 96; gf += NTHR) {
      size_t gidx = boff + (size_t)(gf >> 5) * H + wgi * SLICE + (gf & 31);
      bih_s[gf] = loadS(b_ih, isbf, gidx);
      bhh_s[gf] = loadS(b_hh, isbf, gidx);
    }
  }

  // ---- per-lane poll pointer + threshold offset (wave 0 only) ----
  const unsigned* pollp = nullptr;
  int polloff = 0;
  if (wave == 0) {
    if (grp == 0) {
      if (lane == 0) { pollp = flagp(flags, 1, wgi, 2); polloff = -2; }
    } else if (grp == 1) {
      if      (lane == 0)  { pollp = flagp(flags, 0, wgi, 0);       polloff = 0;  }
      else if (lane <= 24) { pollp = flagp(flags, 1, lane - 1, 0);  polloff = 0;  }
      else if (lane <= 48) { pollp = flagp(flags, 2, lane - 25, 0); polloff = -2; }
    } else if (grp == 2) {
      if      (lane < 24)  { pollp = flagp(flags, 1, lane, 1);      polloff = 0;  }
      else if (lane == 24) { pollp = flagp(flags, 3, wgi, 1);       polloff = -1; }
    } else {
      if      (lane == 0)  { pollp = flagp(flags, 2, wgi, 1);       polloff = -1; }
      else if (lane <= 24) { pollp = flagp(flags, 3, lane - 1, 0);  polloff = 0;  }
    }
  }

  // ---- load this wave's B-fragments (16 gate rows x K=768) into registers --
  const void* Wmat = (grp == 0 || grp == 2) ? w_ih : w_hh;
  const size_t woff = (grp >= 2) ? (size_t)G3 * H : 0;
  const int gate   = wave >> 1;                       // 0=r,1=z,2=n
  const int gfbase = gate * SLICE + (wave & 1) * 16;  // within-wg flat gate base
  const int nrow   = gate * H + wgi * SLICE + (wave & 1) * 16 + (lane & 15);
  const size_t wbase = woff + (size_t)nrow * H + quad * 8;

  short8 bfrag[24];
  #pragma unroll
  for (int kk = 0; kk < 24; kk++)
    bfrag[kk] = loadW8(Wmat, isbf, wbase + kk * 32);

  // staging decomposition: thread -> (row b, 32-elem segment = 4 x 16B units)
  const int sb  = tid / 24;            // 0..15
  const int seg = tid % 24;            // 0..23
  const int sx  = sb & 7;              // staging swizzle key

  // combine decomposition: 256 threads, pairs of columns
  const int pb = tid >> 4;             // batch
  const int pj = (tid & 15) * 2;       // column pair
  const bool pact = isL && (tid < BATCH * SLICE / 2);

  const int lag = (grp == 1) ? 1 : ((grp == 2) ? 2 : ((grp == 3) ? 4 : 0));

  __syncthreads();

  for (int t = 0; t < TLEN + 4; t++) {
    const int tau = t - lag;
    const bool active = (tau >= 0) && (tau < TLEN);

    if (active) {
      // ---- dependency wait ----
      if (wave == 0) {
        for (;;) {
          int v = pollp ? (int)agent_ld32(pollp) : 0x7FFFFFFF;
          if (__ballot(v < t + polloff) == 0ull) break;
          __builtin_amdgcn_s_sleep(1);
        }
      }
      __syncthreads();

      // ---- early-issue combine-phase gx loads (producer has >=1 tick lead)
      unsigned long long gr01 = 0, gz01 = 0, gn01 = 0;
      if (pact) {
        const float* gxr = ((grp == 1) ? gxbuf1 : gxbuf2)
            + ((size_t)((tau & 3) * WPG + wgi) * BATCH + pb) * 96;
        gr01 = agent_ld64(gxr + pj);
        gz01 = agent_ld64(gxr + 32 + pj);
        gn01 = agent_ld64(gxr + 64 + pj);
      }

      // ---- stage A tile (16 x 768) into LDS (XOR-swizzled units) ----
      if (grp == 0) {
        const size_t srcbase = ((size_t)sb * TLEN + tau) * H + seg * 32;
        #pragma unroll
        for (int i = 0; i < 4; i++) {
          short8 v = loadA8(x, isbf, srcbase + i * 8);
          *(short8*)&h_lds[sb * H + (((seg * 4 + i) ^ sx) * 8)] = v;
        }
      } else {
        const int hstep = (grp == 3) ? (t - 5) : (t - 2);
        u32x4 r4[4];
        if (hstep >= 0) {
          const ushort* src = (grp == 3)
              ? y2 + ((size_t)sb * TLEN + hstep) * H + seg * 32
              : h1buf + (size_t)(hstep & 3) * (BATCH * H) + (size_t)sb * H + seg * 32;
          ld64B_agent(src, r4);
        } else {
          r4[0] = (u32x4){0u, 0u, 0u, 0u};
          r4[1] = r4[0]; r4[2] = r4[0]; r4[3] = r4[0];
        }
        #pragma unroll
        for (int j = 0; j < 4; j++)
          *(u32x4*)&h_lds[sb * H + (((seg * 4 + j) ^ sx) * 8)] = r4[j];
      }
      __syncthreads();

      // ---- MFMA: A from LDS (swizzled read), B from registers ----
      const int ar  = lane & 15;
      const int arx = ar & 7;
      const ushort* abase = &h_lds[ar * H];
      f32x4 acc0 = {0.f, 0.f, 0.f, 0.f}, acc1 = {0.f, 0.f, 0.f, 0.f};
      #pragma unroll
      for (int kk = 0; kk < 12; kk++) {
        short8 a0 = *(const short8*)&abase[((quad + 4 * kk) ^ arx) * 8];
        short8 a1 = *(const short8*)&abase[((quad + 4 * (kk + 12)) ^ arx) * 8];
        acc0 = __builtin_amdgcn_mfma_f32_16x16x32_bf16(a0, bfrag[kk],      acc0, 0, 0, 0);
        acc1 = __builtin_amdgcn_mfma_f32_16x16x32_bf16(a1, bfrag[kk + 12], acc1, 0, 0, 0);
      }
      f32x4 acc = acc0 + acc1;

      // ---- stage C tile to LDS ----
      #pragma unroll
      for (int i = 0; i < 4; i++)
        ghs[(gfbase + (lane & 15)) * 17 + quad * 4 + i] = acc[i];
      __syncthreads();

      if (!isL) {
        // pack gx slice [16][96] f32 -> coalesced 8B agent stores
        float* gxout = ((grp == 0) ? gxbuf1 : gxbuf2)
            + ((size_t)(tau & 3) * WPG + wgi) * BATCH * 96;
        const int m  = tid / 24;
        const int c4 = (tid % 24) * 4;
        union { unsigned long long q; float f[2]; } p0, p1;
        p0.f[0] = ghs[(c4 + 0) * 17 + m];
        p0.f[1] = ghs[(c4 + 1) * 17 + m];
        p1.f[0] = ghs[(c4 + 2) * 17 + m];
        p1.f[1] = ghs[(c4 + 3) * 17 + m];
        agent_st64(gxout + (size_t)m * 96 + c4,     p0.q);
        agent_st64(gxout + (size_t)m * 96 + c4 + 2, p1.q);
      } else if (pact) {
        union { unsigned long long q; float f[2]; } ur, uz, un;
        ur.q = gr01; uz.q = gz01; un.q = gn01;
        unsigned hpack = 0;
        #pragma unroll
        for (int s = 0; s < 2; s++) {
          const int j = pj + s;
          float rpre = ur.f[s] + bih_s[j]      + ghs[j * 17 + pb]        + bhh_s[j];
          float zpre = uz.f[s] + bih_s[32 + j] + ghs[(32 + j) * 17 + pb] + bhh_s[32 + j];
          float hn   = ghs[(64 + j) * 17 + pb] + bhh_s[64 + j];
          float r = 1.0f / (1.0f + expf(-rpre));
          float z = 1.0f / (1.0f + expf(-zpre));
          float n = tanhf(un.f[s] + bih_s[64 + j] + r * hn);
          float hnew = (1.0f - z) * n + z * hold[pb * SLICE + j];
          hold[pb * SLICE + j] = hnew;
          hpack |= ((unsigned)f2b(hnew)) << (16 * s);
        }
        if (grp == 1)
          agent_st32(h1buf + (size_t)(tau & 3) * (BATCH * H)
                           + (size_t)pb * H + wgi * SLICE + pj, hpack);
        else
          agent_st32(&y2[((size_t)pb * TLEN + tau) * H + wgi * SLICE + pj], hpack);
      }
    }

    // ---- post completion flag (after vmcnt drain) ----
    __syncthreads();                       // drains vmcnt: comms stores visible
    if (tid < 4) agent_st32(flagp(flags, grp, wgi, tid), (unsigned)(t + 1));
  }
}

// ---------------------------------------------------------------------------
// Final FC (768->512) + bias + exact GELU.  M=16384, N=512, K=768.
// ---------------------------------------------------------------------------
__global__ __launch_bounds__(256) void fc_kernel(
    const ushort* __restrict__ y2,     // [16384][768] bf16 (internal)
    const void* __restrict__ w_fc,     // [512][768]
    const void* __restrict__ b_fc,     // [512]
    const unsigned* __restrict__ dflag,
    void* __restrict__ out)            // [16384][512]
{
  const bool isbf = dflag[0] != 0u;
  const int wave = threadIdx.x >> 6;
  const int lane = threadIdx.x & 63;
  const int col  = lane & 15;
  const int quad = lane >> 4;
  const int m0 = blockIdx.x * 64 + wave * 16;
  const int n0 = blockIdx.y * 64;

  const ushort* arow = y2 + (size_t)(m0 + col) * H + quad * 8;
  const size_t bbase = (size_t)(n0 + col) * H + quad * 8;

  f32x4 acc[4];
  #pragma unroll
  for (int nt = 0; nt < 4; nt++) acc[nt] = (f32x4){0.f, 0.f, 0.f, 0.f};

  for (int kk = 0; kk < 24; kk++) {
    short8 a = *(const short8*)(arow + kk * 32);
    #pragma unroll
    for (int nt = 0; nt < 4; nt++) {
      short8 b = loadA8(w_fc, isbf, bbase + (size_t)nt * 16 * H + kk * 32);
      acc[nt] = __builtin_amdgcn_mfma_f32_16x16x32_bf16(a, b, acc[nt], 0, 0, 0);
    }
  }

  #pragma unroll
  for (int nt = 0; nt < 4; nt++) {
    #pragma unroll
    for (int i = 0; i < 4; i++) {
      int m = m0 + quad * 4 + i;
      int n = n0 + nt * 16 + col;
      float v = acc[nt][i] + loadS(b_fc, isbf, n);
      float g = 0.5f * v * (1.0f + erff(v * 0.70710678118654752f));
      if (isbf) ((ushort*)out)[(size_t)m * DOUT + n] = f2b(g);
      else      ((float*)out)[(size_t)m * DOUT + n] = g;
    }
  }
}

extern "C" void kernel_launch(void* const* d_in, const int* in_sizes, int n_in,
                              void* d_out, int out_size, void* d_ws, size_t ws_size,
                              hipStream_t stream) {
  const void* x    = d_in[0];
  const void* w_ih = d_in[1];
  const void* w_hh = d_in[2];
  const void* b_ih = d_in[3];
  const void* b_hh = d_in[4];
  const void* w_fc = d_in[5];
  const void* b_fc = d_in[6];

  char* ws = (char*)d_ws;
  // layout: [0,49152) flags[4][24][4][32] | [49152,49156) dflag |
  //         [53248,151552) h1 (4-deep) | [151552,741376) gx1 (4-deep) |
  //         [741376,1331200) gx2 (4-deep) | [1331200,26497024) y2 (=h2 history)
  unsigned int* flags = (unsigned int*)(ws);
  unsigned int* dflag = (unsigned int*)(ws + 49152);
  ushort* h1buf  = (ushort*)(ws + 53248);
  float*  gxbuf1 = (float*)(ws + 151552);
  float*  gxbuf2 = (float*)(ws + 741376);
  ushort* y2     = (ushort*)(ws + 1331200);

  hipMemsetAsync(ws, 0, 49156, stream);  // flags + dflag only (data is flag-gated)
  scan_kernel<<<dim3(NWG), dim3(NTHR), 0, stream>>>(
      x, w_ih, w_hh, b_ih, b_hh, flags, dflag,
      h1buf, gxbuf1, gxbuf2, y2);
  fc_kernel<<<dim3(16384 / 64, DOUT / 64), dim3(256), 0, stream>>>(
      y2, w_fc, b_fc, dflag, (void*)d_out);
}